// Round 7
// baseline (474.540 us; speedup 1.0000x reference)
//
#include <hip/hip_runtime.h>

#define LOGZERO -10000000000.0f

// Problem constants (fixed shapes from the reference)
constexpr int Bc    = 8;      // batch
constexpr int Tc    = 500;    // time
constexpr int Oc    = 10000;  // vocab
constexpr int NBH   = 64;     // B * W hyps
constexpr int NHYP  = 8;      // hyps per batch (NBH / Bc)
constexpr int SNUM  = 200;    // scoring ids per hyp
constexpr int BLANK = 0;
constexpr int EOSID = 2;

constexpr int TC     = 4;                  // t-rows per block
constexpr int NCHUNK = (Tc + TC - 1) / TC; // 125
constexpr int NSCORE = Bc * NCHUNK;        // 1000 scoring blocks
constexpr int NPAIR  = NHYP * SNUM;        // 1600 (h,k) pairs per batch
constexpr int NP     = 7;                  // pairs per thread: ceil(1600/256)
constexpr int NV4    = Oc / 4;             // 2500 float4 per row
constexpr int NWI    = 39;                 // full 1024B wave-copies per row
constexpr int TAILF  = Oc - NWI * 256;     // 16 tail floats (64 B)
constexpr int TAILB  = NWI * 256;          // 9984

__device__ __forceinline__ float logaddexp_f(float a, float b) {
    float m = fmaxf(a, b);
    return m + log1pf(expf(-fabsf(a - b)));
}

// Fused kernel (two variants):
//   ASYNC=false: R4 staging (reg round-trip float4 loop) — anchor.
//   ASYNC=true : global_load_lds width-16 fire-and-forget staging.
//   blocks [0, NSCORE): score role -> private partial slice (no atomics).
//   blocks [NSCORE, NSCORE+NBH): sweep role -> out = (LOGZERO|eos) - s_prev.
// Idempotent: pure stores, safe to launch repeatedly in one graph.
template<bool ASYNC>
__global__ __launch_bounds__(256, 4) void ctc_main_kernel(
    const float* __restrict__ x,            // (B, T, O)
    const float* __restrict__ r_prev,       // (T, 2, NBH)
    const float* __restrict__ s_prev,       // (NBH, O)
    const int*   __restrict__ xlens,        // (B,)
    const int*   __restrict__ last_ids,     // (NBH,)
    const int*   __restrict__ scoring_ids,  // (NBH, SNUM)
    const int*   __restrict__ olen_p,       // (1,)
    float*       __restrict__ part,         // (NCHUNK, NBH, SNUM) partials
    float*       __restrict__ out)          // (NBH, O)
{
    const int blk = blockIdx.x;
    const int tid = threadIdx.x;

    if (blk >= NSCORE) {
        // ---- sweep role ----
        const int h = blk - NSCORE;
        const int b = h >> 3;
        const int end = xlens[b] - 1;
        const float r0 = r_prev[(size_t)end * (2 * NBH) + h];
        const float r1 = r_prev[(size_t)end * (2 * NBH) + NBH + h];
        const float eos = logaddexp_f(r0, r1);

        const float4* sp4  = (const float4*)(s_prev + (size_t)h * Oc);
        float4*       out4 = (float4*)(out + (size_t)h * Oc);
        for (int idx = tid; idx < NV4; idx += 256) {
            float4 s = sp4[idx];
            int o = idx * 4;
            float4 v;
            v.x = ((o + 0 == EOSID) ? eos : LOGZERO) - s.x;
            v.y = ((o + 1 == EOSID) ? eos : LOGZERO) - s.y;
            v.z = ((o + 2 == EOSID) ? eos : LOGZERO) - s.z;
            v.w = ((o + 3 == EOSID) ? eos : LOGZERO) - s.w;
            out4[idx] = v;
        }
        return;
    }

    // ---- score role ----
    const int c  = blk >> 3;
    const int b  = blk & 7;
    const int t0 = c * TC;

    float* __restrict__ myPart = part + ((size_t)c * NBH + b * NHYP) * SNUM;

    const int ol    = olen_p[0];
    const int start = (ol > 1) ? ol : 1;
    const int tlo   = (ol == 0) ? 0 : start;
    int xlen = xlens[b];
    if (xlen > Tc) xlen = Tc;
    const int lo = (t0 > tlo) ? t0 : tlo;
    const int hi = ((t0 + TC) < xlen) ? (t0 + TC) : xlen;
    if (lo >= hi) {
        for (int p = tid; p < NPAIR; p += 256) myPart[p] = 0.0f;
        return;
    }
    const int nt = hi - lo;

    __shared__ __align__(16) float xrow[Oc];
    __shared__ float phiL[2 * TC * NHYP];   // [sel][ti][j]: sel 0 = no-hit, 1 = hit

    if (tid < nt * NHYP) {
        const int ti = tid >> 3;
        const int j  = tid & 7;
        const int t  = lo + ti;
        if (t == 0) {
            phiL[ti * NHYP + j]             = 0.0f;
            phiL[TC * NHYP + ti * NHYP + j] = 0.0f;
        } else {
            const int h = b * NHYP + j;
            const float r0 = r_prev[(size_t)(t - 1) * (2 * NBH) + h];
            const float r1 = r_prev[(size_t)(t - 1) * (2 * NBH) + NBH + h];
            phiL[ti * NHYP + j]             = logaddexp_f(r0, r1);
            phiL[TC * NHYP + ti * NHYP + j] = r1;
        }
    }

    int   sid[NP];
    int   hoff[NP];
    float acc[NP];
#pragma unroll
    for (int i = 0; i < NP; ++i) {
        acc[i] = 0.0f;
        int p = tid + i * 256;
        if (p < NPAIR) {
            int j = p / SNUM;
            int k = p - j * SNUM;
            int h = b * NHYP + j;
            int s = scoring_ids[h * SNUM + k];
            sid[i]  = s;
            hoff[i] = ((s == last_ids[h]) ? TC * NHYP : 0) + j;
        } else {
            sid[i] = 0; hoff[i] = 0;
        }
    }

    const int lane = tid & 63;
    const int wv   = tid >> 6;

    for (int t = lo, ti = 0; t < hi; ++t, ++ti) {
        const float*  row  = x + (size_t)(b * Tc + t) * Oc;
        const float4* row4 = (const float4*)row;
        float4* x4 = (float4*)xrow;

        if constexpr (ASYNC) {
            // Fire-and-forget global->LDS DMA: each wave issues ~10 independent
            // 1024B copies (64 lanes x 16B, lds dest = uniform base + lane*16).
            for (int i = wv; i < NWI; i += 4) {
                __builtin_amdgcn_global_load_lds(
                    (const __attribute__((address_space(1))) void*)(row4 + i * 64 + lane),
                    (__attribute__((address_space(3))) void*)(x4 + i * 64),
                    16, 0, 0);
            }
            if (tid < TAILF) xrow[TAILB + tid] = row[TAILB + tid];
        } else {
            for (int idx = tid; idx < NV4; idx += 256) {
                x4[idx] = row4[idx];
            }
        }
        __syncthreads();   // drains vmcnt (global_load_lds) + lgkmcnt

        const int tb = ti * NHYP;
#pragma unroll
        for (int i = 0; i < NP; ++i) {
            int p = tid + i * 256;
            if (p < NPAIR) {
                acc[i] += expf(phiL[hoff[i] + tb] + xrow[sid[i]]);
            }
        }
        __syncthreads();
    }

#pragma unroll
    for (int i = 0; i < NP; ++i) {
        int p = tid + i * 256;
        if (p < NPAIR) myPart[p] = acc[i];
    }
}

// Reduce partials over c and scatter into out (skip BLANK/EOS).
__global__ __launch_bounds__(256) void ctc_reduce_scatter_kernel(
    const float* __restrict__ s_prev,       // (NBH, O)
    const int*   __restrict__ scoring_ids,  // (NBH, SNUM)
    const float* __restrict__ part,         // (NCHUNK, NBH, SNUM)
    float*       __restrict__ out)          // (NBH, O)
{
    const int h   = blockIdx.x;
    const int tid = threadIdx.x;
    if (tid < SNUM) {
        float sum = 0.0f;
        const float* p = part + (size_t)h * SNUM + tid;
#pragma unroll 5
        for (int c = 0; c < NCHUNK; ++c) {
            sum += p[(size_t)c * NBH * SNUM];
        }
        int o = scoring_ids[h * SNUM + tid];
        if (o != BLANK && o != EOSID) {
            sum = fmaxf(sum, 1e-37f);
            out[(size_t)h * Oc + o] = logf(sum) - s_prev[(size_t)h * Oc + o];
        }
    }
}

extern "C" void kernel_launch(void* const* d_in, const int* in_sizes, int n_in,
                              void* d_out, int out_size, void* d_ws, size_t ws_size,
                              hipStream_t stream) {
    const float* x           = (const float*)d_in[0];
    const float* r_prev      = (const float*)d_in[1];
    const float* s_prev      = (const float*)d_in[2];
    const int*   xlens       = (const int*)d_in[3];
    const int*   last_ids    = (const int*)d_in[4];
    const int*   scoring_ids = (const int*)d_in[5];
    const int*   olen        = (const int*)d_in[6];
    float* out  = (float*)d_out;
    float* part = (float*)d_ws;  // 6.4 MB

    // MEASUREMENT ROUND: 1x R4-anchor kernel + 10x async-staging kernel.
    // All launches are idempotent (pure stores, identical results), so the
    // final state is correct and dur_us = R4_dur + 10 * t(async_kernel).
    ctc_main_kernel<false><<<NSCORE + NBH, 256, 0, stream>>>(
        x, r_prev, s_prev, xlens, last_ids, scoring_ids, olen, part, out);
#pragma unroll
    for (int r = 0; r < 10; ++r) {
        ctc_main_kernel<true><<<NSCORE + NBH, 256, 0, stream>>>(
            x, r_prev, s_prev, xlens, last_ids, scoring_ids, olen, part, out);
    }
    ctc_reduce_scatter_kernel<<<NBH, 256, 0, stream>>>(
        s_prev, scoring_ids, part, out);
}